// Round 7
// baseline (109.496 us; speedup 1.0000x reference)
//
#include <hip/hip_runtime.h>

// Problem constants (from reference setup_inputs): B=8, N=16384, K=64
#define BB 8
#define NN 16384
#define KK 64
#define GRID_FUSED 2048

#if __has_builtin(__builtin_amdgcn_exp2f)
#define EXP2(x) __builtin_amdgcn_exp2f(x)
#else
#define EXP2(x) exp2f(x)
#endif

typedef float v2f __attribute__((ext_vector_type(2)));

#if __has_builtin(__builtin_elementwise_fma)
#define FMA2(a, b, c) __builtin_elementwise_fma((a), (b), (c))
#else
static __device__ inline v2f FMA2(v2f a, v2f b, v2f c) {
    v2f r; r.x = fmaf(a.x, b.x, c.x); r.y = fmaf(a.y, b.y, c.y); return r;
}
#endif

#define LOG2E 1.44269504088896340736f
// exp(inv*dist) = exp2( CW*dot + CE*(n2+1) ), inv = -12.5, ||w||^2 == 1
#define CW (25.0f * LOG2E)
#define CE (-12.5f * LOG2E)
// feat kept at 16x reference scale -> var is 256x -> eps must be 256*1e-5
// for an EXACT match to reference BN.
#define BN_EPS_SCALED 2.56e-3f

// Workspace layout (float offsets). Every cross-XCD slot is touched ONLY by
// agent-scope atomics (coherence-point ops, no cache maintenance needed).
//   [0..512)     gsumR[8][64] — 8 line-spread replicas (R4 lesson: RMWs into
//   [512..1024)  gssR[8][64]    one 64B line serialize at the coherence point)
//   [1024..1536) sub counters: 32, spaced 16 floats (1 line apart)
//   [1536..1552) root counter
//   [1552..2064) flags: 32 copies, spaced 16
//   [2064..2832) wx/wy/wz tables (3 x 256)
#define WS_GSUM 0
#define WS_GSS  512
#define WS_SUB  1024
#define WS_ROOT 1536
#define WS_FLAG 1552
#define WS_ZERO 2064
#define WS_WX   2064

// ---------------------------------------------------------------------------
// Kernel 0: zero barrier/accumulator region (ws is poisoned 0xAA before every
// timed launch) and precompute scaled kernel directions into SoA (wave-
// uniform k in the hot loop -> s_load path).
// ---------------------------------------------------------------------------
__global__ __launch_bounds__(256) void fkc_prep(
    const float* __restrict__ walpha, const float* __restrict__ wbeta,
    float* __restrict__ ws)
{
    const int t = threadIdx.x;
    for (int i = t; i < WS_ZERO; i += 256) ws[i] = 0.0f;
    float a = walpha[t];
    float b = wbeta[t];
    float sa = __sinf(a);
    ws[WS_WX + t]       = CW * sa * __cosf(b);
    ws[WS_WX + 256 + t] = CW * sa * __sinf(b);
    ws[WS_WX + 512 + t] = CW * __cosf(a);
}

// ---------------------------------------------------------------------------
// Fused kernel v7: one block = 64 points x ALL 64 k. Grid 2048, 256 threads,
// 8 blocks/CU (the proven co-residency geometry).
//
// R5/R6 post-mortem: register-resident feat[32/64] ALWAYS spills — the
// allocator picks 64 VGPRs at 256 threads regardless of launch_bounds/
// waves_per_eu hints (VGPR_Count=64 + 100-700 MB scratch traffic in both
// rounds). v7 therefore keeps feats in LDS (fl[64][65]) and the per-thread
// register footprint at ~50 VGPR: nothing left to spill.
//
// Gather de-replication (R4 carried 4x): 12 coords/point are gathered ONCE
// into an LDS stage by cooperative threads (t = p*4+j: j<3 -> neighbor j of
// point p, 3 scattered loads; j==3 -> own coords, coalesced), then each
// thread (kq = tid>>6, p = tid&63) reads its point's coords from LDS.
// Chip-wide scattered lane-loads drop to the 1.18M minimum (~1.9us/CU of L1
// probes vs ~7.5 in R4). The gather stage aliases fl rows 0..11 (dead once
// coords are in registers; barrier-separated before fl writes begin).
//
// Compute: 16 k per thread (k = kq*16 + r), k wave-uniform -> w tables via
// s_load; result ds_written straight to fl[k][p] (lanes p consecutive ->
// conflict-free). Reduce: t<64 column-sums fl[t][0..63] (stride 65 ->
// (k+i)%32 banks, 2-way only), atomicAdd into replica blk&7. 2048-arrival
// all-relaxed tree barrier (32 sub x 64 -> root -> 32 flag copies, <=64
// spinners/line, s_sleep(8)). BN scale/shift (sum 8 replicas), then 16
// coalesced stores/thread from fl.
// LDS: 64*65*4 + 512 = 17,152 B -> 8 blocks/CU = 137 KB <= 160 KB.
// ---------------------------------------------------------------------------
__global__ __launch_bounds__(256, 8) void fkc_fused(
    const float* __restrict__ normals,   // (B,3,N)
    const int*   __restrict__ nidx,      // (B,N,3) int32
    float* __restrict__ ws,              // layout above
    float* __restrict__ out,             // (B,K,N) final (post BN+ReLU)
    const float* __restrict__ gamma,
    const float* __restrict__ beta)
{
    __shared__ float smem[64 * 65 + 128];   // fl[k][p] = smem[k*65+p]
    float* scs = smem + 64 * 65;            // [64]
    float* shs = smem + 64 * 65 + 64;       // [64]
    // gather stage aliases fl rows 0..11: fpts[q][p] = smem[q*64+p], q=0..11
    // (q = slot*3 + c; slot 0 = own point, 1..3 = neighbors; c = x,y,z)

    const float* wx = ws + WS_WX;
    const float* wy = ws + WS_WX + 256;
    const float* wz = ws + WS_WX + 512;

    const int tid = threadIdx.x;
    const int gid0 = blockIdx.x * 64;
    const int b = gid0 >> 14;            // 64-pt groups never straddle batches
    const int n0 = gid0 & (NN - 1);
    const float* nb = normals + b * 3 * NN;

    // ---- cooperative gather: 12 coords per point, issued ONCE ----
    {
        const int p = tid >> 2;          // point 0..63
        const int j = tid & 3;           // 0..2: neighbor j; 3: own point
        int id;
        if (j == 3) {
            id = n0 + p;                 // own normal (coalesced)
        } else {
            id = nidx[(b * NN + n0 + p) * 3 + j];   // scattered
        }
        const int slot = (j + 1) & 3;    // own->0, nbr j->j+1
        smem[(slot * 3 + 0) * 64 + p] = nb[id];
        smem[(slot * 3 + 1) * 64 + p] = nb[NN + id];
        smem[(slot * 3 + 2) * 64 + p] = nb[2 * NN + id];
    }
    __syncthreads();

    // ---- every thread loads its point's 12 coords into registers ----
    const int kq = tid >> 6;             // k quarter 0..3 (== wave id)
    const int p  = tid & 63;             // point within block
    float fx[4], fy[4], fz[4];
#pragma unroll
    for (int i = 0; i < 4; ++i) {
        fx[i] = smem[(i * 3 + 0) * 64 + p];
        fy[i] = smem[(i * 3 + 1) * 64 + p];
        fz[i] = smem[(i * 3 + 2) * 64 + p];
    }
    __syncthreads();   // fpts region is dead; fl writes may now overwrite it

    // Pack p-pairs for v_pk_fma_f32.
    v2f fx01 = {fx[0], fx[1]}, fx23 = {fx[2], fx[3]};
    v2f fy01 = {fy[0], fy[1]}, fy23 = {fy[2], fy[3]};
    v2f fz01 = {fz[0], fz[1]}, fz23 = {fz[2], fz[3]};
    v2f e01, e23;
    {
        v2f n2a = FMA2(fx01, fx01, FMA2(fy01, fy01, fz01 * fz01));
        v2f n2b = FMA2(fx23, fx23, FMA2(fy23, fy23, fz23 * fz23));
        e01 = CE * (n2a + 1.0f);
        e23 = CE * (n2b + 1.0f);
    }

    // ---- 16 k per thread; write straight to fl (no register array) ----
#pragma unroll
    for (int r = 0; r < 16; ++r) {
        const int k = kq * 16 + r;       // wave-uniform -> s_load for w
        v2f acc01 = {0.0f, 0.0f}, acc23 = {0.0f, 0.0f};
#pragma unroll
        for (int m = 0; m < 4; ++m) {
            const int wi = (k << 2) + m;
            float wxv = wx[wi], wyv = wy[wi], wzv = wz[wi];
            v2f wx2 = {wxv, wxv}, wy2 = {wyv, wyv}, wz2 = {wzv, wzv};
            v2f a01 = FMA2(fz01, wz2, FMA2(fy01, wy2, FMA2(fx01, wx2, e01)));
            v2f a23 = FMA2(fz23, wz2, FMA2(fy23, wy2, FMA2(fx23, wx2, e23)));
            v2f x01 = {EXP2(a01.x), EXP2(a01.y)};
            v2f x23 = {EXP2(a23.x), EXP2(a23.y)};
            acc01 += x01;
            acc23 += x23;
        }
        v2f t2 = acc01 + acc23;
        smem[k * 65 + p] = t2.x + t2.y;  // lanes p consecutive: conflict-free
    }
    __syncthreads();

    // ---- per-block reduce: thread k<64 sums its channel over 64 points ----
    // addr k*65+i -> bank (k+i)%32: 2 lanes/bank only (free per m136).
    const int jrep = blockIdx.x & 7;
    if (tid < 64) {
        const int base = tid * 65;
        float s = 0.0f, ss = 0.0f;
#pragma unroll
        for (int i = 0; i < 64; ++i) {
            float v = smem[base + i];
            s += v;
            ss = fmaf(v, v, ss);
        }
        atomicAdd(&ws[WS_GSUM + jrep * 64 + tid], s);
        atomicAdd(&ws[WS_GSS  + jrep * 64 + tid], ss);
    }

    // Drain vmcnt: this block's replica RMWs have reached the coherence
    // point before tid0 touches the barrier counters.
    __syncthreads();

    // ---- all-relaxed 2-level tree barrier over 2048 blocks ----
    if (tid == 0) {
        const int sg = blockIdx.x & 31;  // 32 subgroups of 64 blocks
        unsigned* sub  = (unsigned*)(ws + WS_SUB)  + sg * 16;
        unsigned* root = (unsigned*)(ws + WS_ROOT);
        unsigned* flg  = (unsigned*)(ws + WS_FLAG) + sg * 16;

        unsigned old = __hip_atomic_fetch_add(sub, 1u, __ATOMIC_RELAXED,
                                              __HIP_MEMORY_SCOPE_AGENT);
        if (old == 63u) {   // last of the 64 blocks in subgroup sg
            unsigned r = __hip_atomic_fetch_add(root, 1u, __ATOMIC_RELAXED,
                                                __HIP_MEMORY_SCOPE_AGENT);
            if (r == 31u) { // all 2048 blocks have arrived
#pragma unroll
                for (int jj = 0; jj < 32; ++jj) {
                    unsigned* f = (unsigned*)(ws + WS_FLAG) + jj * 16;
                    __hip_atomic_store(f, 1u, __ATOMIC_RELAXED,
                                       __HIP_MEMORY_SCOPE_AGENT);
                }
            }
        }
        // Relaxed coherence-point polls (no cache maintenance), <=64
        // spinners per flag line, s_sleep(8) ~0.2us wake granularity.
        // Bounded: violated co-residency shows as FAILED, never a hang.
        int polls = 0;
        while (__hip_atomic_load(flg, __ATOMIC_RELAXED,
                                 __HIP_MEMORY_SCOPE_AGENT) == 0u) {
            __builtin_amdgcn_s_sleep(8);
            if (++polls > 300000) break;
        }
        __asm__ __volatile__("" ::: "memory");  // no hoisting past the spin
    }
    __syncthreads();

    // ---- BN scale/shift for all 64 k (sum the 8 replicas) ----
    if (tid < 64) {
        float s = 0.0f, q = 0.0f;
#pragma unroll
        for (int j = 0; j < 8; ++j) {
            s += __hip_atomic_load(ws + WS_GSUM + j * 64 + tid,
                                   __ATOMIC_RELAXED, __HIP_MEMORY_SCOPE_AGENT);
            q += __hip_atomic_load(ws + WS_GSS + j * 64 + tid,
                                   __ATOMIC_RELAXED, __HIP_MEMORY_SCOPE_AGENT);
        }
        const float invM = 1.0f / (float)(BB * NN);
        float mean = s * invM;
        float var = fmaf(-mean, mean, q * invM);  // biased variance (x16)
        float sc = gamma[tid] * rsqrtf(var + BN_EPS_SCALED);
        scs[tid] = sc;
        shs[tid] = fmaf(-mean, sc, beta[tid]);
    }
    __syncthreads();

    // ---- apply BN+ReLU from fl; 16 coalesced 256B wave-stores/thread ----
    float* obase = out + b * KK * NN + n0 + p;
#pragma unroll
    for (int r = 0; r < 16; ++r) {
        const int k = kq * 16 + r;
        float v = smem[k * 65 + p];
        obase[k * NN] = fmaxf(fmaf(v, scs[k], shs[k]), 0.0f);
    }
}

// ---------------------------------------------------------------------------
// FALLBACK PATH (the proven 110.7 us structure): main writes pre-BN feats +
// atomics (replica 0 only); apply does BN+ReLU in a second pass. Used only if
// the host-side occupancy check says the fused kernel can't be co-resident
// (also the spill tripwire: VGPR>64 -> occ<8 -> fallback).
// ---------------------------------------------------------------------------
__global__ __launch_bounds__(256, 8) void fkc_main(
    const float* __restrict__ normals, const int* __restrict__ nidx,
    float* __restrict__ ws,
    float* __restrict__ out)
{
    __shared__ float fl[16][257];
    __shared__ float ps[16][17], pq[16][17];

    const float* wx = ws + WS_WX;
    const float* wy = ws + WS_WX + 256;
    const float* wz = ws + WS_WX + 512;
    float* gsum = ws + WS_GSUM;
    float* gss  = ws + WS_GSS;

    const int tid = threadIdx.x;
    const int pg = blockIdx.x >> 2;
    const int k0 = (blockIdx.x & 3) * 16;
    const int gid = pg * 256 + tid;
    const int b = gid >> 14;
    const int n = gid & (NN - 1);
    const float* nb = normals + b * 3 * NN;

    float fx[4], fy[4], fz[4];
    fx[0] = nb[n];
    fy[0] = nb[NN + n];
    fz[0] = nb[2 * NN + n];
    const int ibase = (b * NN + n) * 3;
#pragma unroll
    for (int j = 0; j < 3; ++j) {
        int id = nidx[ibase + j];
        fx[j + 1] = nb[id];
        fy[j + 1] = nb[NN + id];
        fz[j + 1] = nb[2 * NN + id];
    }

    v2f fx01 = {fx[0], fx[1]}, fx23 = {fx[2], fx[3]};
    v2f fy01 = {fy[0], fy[1]}, fy23 = {fy[2], fy[3]};
    v2f fz01 = {fz[0], fz[1]}, fz23 = {fz[2], fz[3]};
    v2f e01, e23;
    {
        v2f n2a = FMA2(fx01, fx01, FMA2(fy01, fy01, fz01 * fz01));
        v2f n2b = FMA2(fx23, fx23, FMA2(fy23, fy23, fz23 * fz23));
        e01 = CE * (n2a + 1.0f);
        e23 = CE * (n2b + 1.0f);
    }

    float* orow = out + (b * KK + k0) * NN + n;
#pragma unroll
    for (int kk = 0; kk < 16; ++kk) {
        v2f acc01 = {0.0f, 0.0f}, acc23 = {0.0f, 0.0f};
#pragma unroll
        for (int m = 0; m < 4; ++m) {
            const int wi = ((k0 + kk) << 2) + m;
            float wxv = wx[wi], wyv = wy[wi], wzv = wz[wi];
            v2f wx2 = {wxv, wxv}, wy2 = {wyv, wyv}, wz2 = {wzv, wzv};
            v2f a01 = FMA2(fz01, wz2, FMA2(fy01, wy2, FMA2(fx01, wx2, e01)));
            v2f a23 = FMA2(fz23, wz2, FMA2(fy23, wy2, FMA2(fx23, wx2, e23)));
            v2f x01 = {EXP2(a01.x), EXP2(a01.y)};
            v2f x23 = {EXP2(a23.x), EXP2(a23.y)};
            acc01 += x01;
            acc23 += x23;
        }
        v2f t2 = acc01 + acc23;
        float acc = t2.x + t2.y;
        orow[kk * NN] = acc;
        fl[kk][tid] = acc;
    }
    __syncthreads();

    {
        const int k = tid & 15;
        const int part = tid >> 4;
        float s = 0.0f, ss = 0.0f;
#pragma unroll
        for (int r = 0; r < 16; ++r) {
            float v = fl[k][part * 16 + r];
            s += v;
            ss = fmaf(v, v, ss);
        }
        ps[k][part] = s;
        pq[k][part] = ss;
    }
    __syncthreads();

    if (tid < 16) {
        float s = 0.0f;
#pragma unroll
        for (int r = 0; r < 16; ++r) s += ps[tid][r];
        atomicAdd(&gsum[k0 + tid], s);
    } else if (tid < 32) {
        const int kk = tid - 16;
        float ss = 0.0f;
#pragma unroll
        for (int r = 0; r < 16; ++r) ss += pq[kk][r];
        atomicAdd(&gss[k0 + kk], ss);
    }
}

__global__ __launch_bounds__(256) void fkc_apply(
    float4* __restrict__ out4,
    const float* __restrict__ ws,
    const float* __restrict__ gamma, const float* __restrict__ beta)
{
    const int i = blockIdx.x * 256 + threadIdx.x;
    const int k = (i >> 12) & (KK - 1);      // uniform within block

    const float invM = 1.0f / (float)(BB * NN);
    float mean = ws[WS_GSUM + k] * invM;
    float var = fmaf(-mean, mean, ws[WS_GSS + k] * invM);
    float sc = gamma[k] * rsqrtf(var + BN_EPS_SCALED);
    float sh = fmaf(-mean, sc, beta[k]);

    float4 v = out4[i];
    v.x = fmaxf(fmaf(v.x, sc, sh), 0.0f);
    v.y = fmaxf(fmaf(v.y, sc, sh), 0.0f);
    v.z = fmaxf(fmaf(v.z, sc, sh), 0.0f);
    v.w = fmaxf(fmaf(v.w, sc, sh), 0.0f);
    out4[i] = v;
}

extern "C" void kernel_launch(void* const* d_in, const int* in_sizes, int n_in,
                              void* d_out, int out_size, void* d_ws, size_t ws_size,
                              hipStream_t stream) {
    const float* normals = (const float*)d_in[0];
    const int*   nidx    = (const int*)d_in[1];
    const float* walpha  = (const float*)d_in[2];
    const float* wbeta   = (const float*)d_in[3];
    const float* gamma   = (const float*)d_in[4];
    const float* beta    = (const float*)d_in[5];
    float* out = (float*)d_out;
    float* ws = (float*)d_ws;

    // One-time host-side co-residency check (queries only — capture-safe).
    // Fused path needs all 2048 blocks resident (8 blocks/CU). This is also
    // the spill tripwire: VGPR>64 -> occ<8 -> proven two-pass fallback.
    static int use_fused = -1;
    if (use_fused < 0) {
        int occ = 0, ncu = 0, dev = 0;
        hipError_t e1 = hipOccupancyMaxActiveBlocksPerMultiprocessor(
            &occ, fkc_fused, 256, 0);
        hipGetDevice(&dev);
        hipError_t e2 = hipDeviceGetAttribute(
            &ncu, hipDeviceAttributeMultiprocessorCount, dev);
        use_fused = (e1 == hipSuccess && e2 == hipSuccess &&
                     (long)occ * ncu >= GRID_FUSED) ? 1 : 0;
    }

    fkc_prep<<<1, 256, 0, stream>>>(walpha, wbeta, ws);
    if (use_fused) {
        fkc_fused<<<GRID_FUSED, 256, 0, stream>>>(
            normals, nidx, ws, out, gamma, beta);
    } else {
        fkc_main<<<2048, 256, 0, stream>>>(normals, nidx, ws, out);
        fkc_apply<<<8192, 256, 0, stream>>>((float4*)out, ws, gamma, beta);
    }
}